// Round 8
// baseline (183.802 us; speedup 1.0000x reference)
//
#include <hip/hip_runtime.h>

typedef __attribute__((ext_vector_type(8))) __bf16 bf16x8;
typedef __attribute__((ext_vector_type(4))) float f32x4;
typedef unsigned short u16;
typedef unsigned int u32;

#define VMCNT(n) asm volatile("s_waitcnt vmcnt(" #n ")" ::: "memory")
#define LGKMCNT0 asm volatile("s_waitcnt lgkmcnt(0)" ::: "memory")

__device__ __forceinline__ u16 f2bf(float f) {
  union { float f; u32 u; } v; v.f = f;
  u32 r = v.u + 0x7FFFu + ((v.u >> 16) & 1u);
  return (u16)(r >> 16);
}
__device__ __forceinline__ float fexp2(float x) {  // 2^x via v_exp_f32
  float r; asm("v_exp_f32 %0, %1" : "=v"(r) : "v"(x)); return r;
}

// ---------------- cast x fp32 -> bf16 (4 elems/thread) ----------------
__global__ __launch_bounds__(256) void cast_x_kernel(const float* __restrict__ x,
                                                     u16* __restrict__ xb, int n4) {
  int i = blockIdx.x * 256 + threadIdx.x;
  if (i >= n4) return;
  float4 v = reinterpret_cast<const float4*>(x)[i];
  ushort4 o;
  o.x = f2bf(v.x); o.y = f2bf(v.y); o.z = f2bf(v.z); o.w = f2bf(v.w);
  reinterpret_cast<ushort4*>(xb)[i] = o;
}

// ------- transpose weights: Wt[u][d] = W[d][u], fp32 -> bf16 ----------
__global__ __launch_bounds__(1024) void transpose_w_kernel(const float* __restrict__ Wq,
                                                           const float* __restrict__ Wk,
                                                           const float* __restrict__ Wv,
                                                           u16* __restrict__ Wt) {
  const float* src = blockIdx.z == 0 ? Wq : (blockIdx.z == 1 ? Wk : Wv);
  u16* dst = Wt + (size_t)blockIdx.z * 512 * 512;
  __shared__ float tile[32][33];
  int u0 = blockIdx.x * 32, d0 = blockIdx.y * 32;
  tile[threadIdx.y][threadIdx.x] = src[(d0 + threadIdx.y) * 512 + u0 + threadIdx.x];
  __syncthreads();
  dst[(u0 + threadIdx.y) * 512 + d0 + threadIdx.x] = f2bf(tile[threadIdx.x][threadIdx.y]);
}

// ---------------- QKV projection: 128x128 tile, ring-3 counted-vmcnt ----
// z==2 (V) writes Vt2[b][kt][u][32] (kt = s>>5): pv stages contiguous tiles.
__global__ __launch_bounds__(256) void qkv_kernel(const u16* __restrict__ Xb,
                                                  const u16* __restrict__ Wt3,
                                                  u16* __restrict__ Q, u16* __restrict__ K,
                                                  u16* __restrict__ Vt2) {
  __shared__ u16 As[3][128 * 32], Bs[3][128 * 32];
  const int bm = blockIdx.y * 128;
  const int bn = blockIdx.x * 128;
  const int z = blockIdx.z;
  const u16* A = Xb + (size_t)bm * 512;
  const u16* Bt = Wt3 + (size_t)z * 512 * 512 + (size_t)bn * 512;

  const int t = threadIdx.x;
  const int lane = t & 63;
  const int w = t >> 6;
  const int wr = w >> 1, wc = w & 1;
  const int la = lane & 15;
  const int q = lane >> 4;
  f32x4 acc[4][4] = {};

  auto stage = [&](int buf, int kt) {
    const int k0 = kt * 32;
#pragma unroll
    for (int it = 0; it < 2; ++it) {    // A: 128 rows -> 512 chunks
      int c = it * 256 + t, row = c >> 2;
      int col = ((c & 3) ^ ((row >> 1) & 3)) << 3;
      __builtin_amdgcn_global_load_lds(
          (const __attribute__((address_space(1))) void*)(A + (size_t)row * 512 + k0 + col),
          (__attribute__((address_space(3))) void*)(&As[buf][c * 8]), 16, 0, 0);
    }
#pragma unroll
    for (int it = 0; it < 2; ++it) {    // B: 128 rows -> 512 chunks
      int c = it * 256 + t, row = c >> 2;
      int col = ((c & 3) ^ ((row >> 1) & 3)) << 3;
      __builtin_amdgcn_global_load_lds(
          (const __attribute__((address_space(1))) void*)(Bt + (size_t)row * 512 + k0 + col),
          (__attribute__((address_space(3))) void*)(&Bs[buf][c * 8]), 16, 0, 0);
    }
  };

  auto body = [&](int buf) {
    bf16x8 a[4], b[4];
#pragma unroll
    for (int i = 0; i < 4; ++i) {
      int row = wr * 64 + i * 16 + la;
      a[i] = *reinterpret_cast<const bf16x8*>(&As[buf][row * 32 + ((q ^ ((row >> 1) & 3)) << 3)]);
    }
#pragma unroll
    for (int j = 0; j < 4; ++j) {
      int row = wc * 64 + j * 16 + la;
      b[j] = *reinterpret_cast<const bf16x8*>(&Bs[buf][row * 32 + ((q ^ ((row >> 1) & 3)) << 3)]);
    }
    __builtin_amdgcn_s_setprio(1);
#pragma unroll
    for (int i = 0; i < 4; ++i)
#pragma unroll
      for (int j = 0; j < 4; ++j)
        acc[i][j] = __builtin_amdgcn_mfma_f32_16x16x32_bf16(a[i], b[j], acc[i][j], 0, 0, 0);
    __builtin_amdgcn_s_setprio(0);
  };

  stage(0, 0); stage(1, 1);             // 8 loads/thread in flight
  int cb = 0, sb = 2;
  for (int kt = 0; kt < 14; ++kt) {
    VMCNT(4);                           // tile kt landed; kt+1 flying
    __builtin_amdgcn_s_barrier();       // all waves' kt landed; buf sb free
    stage(sb, kt + 2);
    body(cb);
    cb = (cb == 2) ? 0 : cb + 1;
    sb = (sb == 2) ? 0 : sb + 1;
  }
  VMCNT(4); __builtin_amdgcn_s_barrier(); body(2);   // kt=14 -> buf 14%3=2
  VMCNT(0); __builtin_amdgcn_s_barrier(); body(0);   // kt=15 -> buf 0

  const int r0 = q * 4, cn = lane & 15;
  if (z < 2) {
    u16* out = (z == 0) ? Q : K;
#pragma unroll
    for (int i = 0; i < 4; ++i)
#pragma unroll
      for (int j = 0; j < 4; ++j)
#pragma unroll
        for (int r = 0; r < 4; ++r) {
          int m = bm + 64 * wr + 16 * i + r0 + r;
          int n = bn + 64 * wc + 16 * j + cn;
          out[(size_t)m * 512 + n] = f2bf(acc[i][j][r]);
        }
  } else {
#pragma unroll
    for (int i = 0; i < 4; ++i)
#pragma unroll
      for (int j = 0; j < 4; ++j)
#pragma unroll
        for (int r = 0; r < 4; ++r) {
          int m = bm + 64 * wr + 16 * i + r0 + r;
          int u = bn + 64 * wc + 16 * j + cn;
          int b = m >> 11, s = m & 2047;
          // Vt2[b][kt=s>>5][u][s&31]
          Vt2[(((size_t)b * 64 + (s >> 5)) * 512 + u) * 32 + (s & 31)] = f2bf(acc[i][j][r]);
        }
  }
}

// ------ P = exp(Q K^T / sqrt(512)) -> bf16: 256x256, ring-4 ------
// Output layout S2[b][kt][q][32] (kt = k>>5): pv stages contiguous tiles.
__global__ __launch_bounds__(512) void scores8_kernel(const u16* __restrict__ Q,
                                                      const u16* __restrict__ K,
                                                      u16* __restrict__ S2) {
  __shared__ u16 ring[4][2][256 * 32];  // [buf][A=0/B=1][256 rows][32 k]
  const int bb = blockIdx.x;            // batch -> XCD
  const int bm = blockIdx.y * 256;
  const int bn = blockIdx.z * 256;
  const u16* Aq = Q + (size_t)(bb * 2048 + bm) * 512;
  const u16* Bk = K + (size_t)(bb * 2048 + bn) * 512;

  const int t = threadIdx.x;
  const int lane = t & 63;
  const int wid = t >> 6;
  const int wm = wid >> 2, wn = wid & 3;
  const int la = lane & 15;
  const int q = lane >> 4;              // k-slot 0..3 (8 elems each)

  f32x4 acc[8][4] = {};

  auto stage = [&](int kt) {
    const int r = kt & 3;
    const int koff = kt * 32;
#pragma unroll
    for (int half = 0; half < 2; ++half) {
      int c = half * 512 + t;
      int row = c >> 2;
      int col = ((c & 3) ^ ((row >> 1) & 3)) << 3;   // inverse swizzle on source
      __builtin_amdgcn_global_load_lds(
          (const __attribute__((address_space(1))) void*)(Aq + (size_t)row * 512 + koff + col),
          (__attribute__((address_space(3))) void*)(&ring[r][0][c * 8]), 16, 0, 0);
      __builtin_amdgcn_global_load_lds(
          (const __attribute__((address_space(1))) void*)(Bk + (size_t)row * 512 + koff + col),
          (__attribute__((address_space(3))) void*)(&ring[r][1][c * 8]), 16, 0, 0);
    }
  };

  auto body = [&](int kt) {
    const int r = kt & 3;
    const u16* At = ring[r][0];
    const u16* Bt = ring[r][1];
    bf16x8 bfr[4], afr[8];
#pragma unroll
    for (int j = 0; j < 4; ++j) {
      int row = wn * 64 + j * 16 + la;
      bfr[j] = *reinterpret_cast<const bf16x8*>(Bt + row * 32 + ((q ^ ((row >> 1) & 3)) << 3));
    }
#pragma unroll
    for (int i = 0; i < 8; ++i) {
      int row = wm * 128 + i * 16 + la;
      afr[i] = *reinterpret_cast<const bf16x8*>(At + row * 32 + ((q ^ ((row >> 1) & 3)) << 3));
    }
    __builtin_amdgcn_s_setprio(1);
#pragma unroll
    for (int i = 0; i < 8; ++i)
#pragma unroll
      for (int j = 0; j < 4; ++j)
        acc[i][j] = __builtin_amdgcn_mfma_f32_16x16x32_bf16(afr[i], bfr[j], acc[i][j], 0, 0, 0);
    __builtin_amdgcn_s_setprio(0);
  };

  stage(0); stage(1); stage(2);         // 12 loads/thread in flight
  for (int kt = 0; kt < 13; ++kt) {
    VMCNT(8);                           // kt's 4 loads landed; kt+1/kt+2 fly
    __builtin_amdgcn_s_barrier();       // all waves' kt landed; buf[(kt+3)&3] free
    stage(kt + 3);
    body(kt);
  }
  VMCNT(8); __builtin_amdgcn_s_barrier(); body(13);
  VMCNT(4); __builtin_amdgcn_s_barrier(); body(14);
  VMCNT(0); __builtin_amdgcn_s_barrier(); body(15);

  const float scale = 0.06375872127f;   // log2(e)/sqrt(512)
  const int r0h = q * 4;
#pragma unroll
  for (int i = 0; i < 8; ++i)
#pragma unroll
    for (int j = 0; j < 4; ++j) {
      int n = bn + wn * 64 + j * 16;                 // k-col base (la added below)
      int kt_j = n >> 5;
      int ke_j = (n & 31) + la;                      // no carry: (n&31) in {0,16}, la<16
      u16* dst = S2 + ((size_t)(bb * 64 + kt_j) * 2048) * 32 + ke_j;
#pragma unroll
      for (int r = 0; r < 4; ++r) {
        int m = bm + wm * 128 + i * 16 + r0h + r;
        dst[(size_t)m * 32] = f2bf(fexp2(acc[i][j][r] * scale));
      }
    }
}

// ---- out = (P * V) / rowsum(P): 128x128, BK=64, k-split, A-DIRECT ----
// Round-7 post-mortem: additive per-step critical path (stage+vmcnt+bar+
// ds_read+lgkm+MFMA all 25-35%) -> remove whole terms. A-fragment of the
// S2 tile layout is DIRECTLY loadable from global with perfect coalescing
// (lane(la,q) reads tile[row16+la][q*8..]: 16 rows x 64B = 1KB contiguous
// per wave-instr), so A skips LDS entirely: 2-deep register pipeline
// (named aA/aB sets, 2-step unroll). B keeps ring-3 LDS + XOR swizzle.
// Per step/wave: 4 global dwordx4 + 2 gload_lds + 4 ds_read + 16 MFMA.
// vmcnt ledger (issue a(s+1) then B(s+2) each step): at top of s+1
// outstanding = B(s+1)x2, a(s+1)x4, B(s+2)x2 -> VMCNT(2) drains exactly
// B(s+1)+a(s+1). One barrier/step. launch_bounds(512,4): 2 blocks/CU.
__global__ __launch_bounds__(512, 4) void pv_kernel(const u16* __restrict__ S2,
                                                    const u16* __restrict__ Vt2,
                                                    float* __restrict__ out) {
  __shared__ __align__(16) char smem[65536];      // Bs[3][8192] u16 | epilogue overlay
  __shared__ float larr2[2][128];                 // rowsum halves (per wk)
  u16* Bs = (u16*)smem;                           // [3][128*64]
  float* scratch = (float*)smem;                  // epilogue overlay (64KB)

  const int id = blockIdx.x;
  const int b = id & 7;                 // batch == XCD
  const int local = id >> 3;            // 0..63
  const int bn = (local & 3) * 128;     // u cols
  const int bm = (local >> 2) * 128;    // q rows

  // S2[b][kt][q][32]: tile base (b,kt,bm) = A2 + kt*65536 (+row*32)
  const u16* A2 = S2 + ((size_t)b * 64 * 2048 + (size_t)bm) * 32;
  // Vt2[b][kt][u][32]: tile base (b,kt,bn) = B2 + kt*16384 (+row*32)
  const u16* B2 = Vt2 + ((size_t)b * 64 * 512 + (size_t)bn) * 32;

  const int t = threadIdx.x;            // 0..511
  const int lane = t & 63;
  const int wid = t >> 6;               // 0..7
  const int wm = (wid >> 2) & 1;        // q 64-row block
  const int wn = (wid >> 1) & 1;        // u 64-col block
  const int wk = wid & 1;               // k half (32 of each BK=64)
  const int la = lane & 15;
  const int q = lane >> 4;

  f32x4 acc[4][4] = {};
  float lacc[4] = {0.f, 0.f, 0.f, 0.f};

  // direct A pointer: tile (2s+wk), row (wm*64 + i*16 + la), elems q*8..
  const u16* aPtr = A2 + (size_t)wk * 65536 + (size_t)(wm * 64 + la) * 32 + q * 8;

  auto loadA = [&](bf16x8 (&dst)[4]) {  // 4 global dwordx4, then bump to next step
#pragma unroll
    for (int i = 0; i < 4; ++i)
      dst[i] = *reinterpret_cast<const bf16x8*>(aPtr + i * 512);
    aPtr += 131072;                     // 2 k-tiles = one BK=64 step
  };

  auto stageB = [&](int s) {            // 2 gload_lds/thread; inverse swizzle on src
    const int buf = s % 3;
#pragma unroll
    for (int it = 0; it < 2; ++it) {
      int c = it * 512 + t;             // 1024 chunks = [128 u][64 k]
      int row = c >> 3, pslot = c & 7;
      int lslot = pslot ^ (row & 7);
      __builtin_amdgcn_global_load_lds(
          (const __attribute__((address_space(1))) void*)(
              B2 + (size_t)(2 * s + (lslot >> 2)) * 16384 + row * 32 + (lslot & 3) * 8),
          (__attribute__((address_space(3))) void*)(Bs + buf * 8192 + c * 8), 16, 0, 0);
    }
  };

  bf16x8 aA[4], aB[4], bb[4];
  auto rdB = [&](int s) {               // 4 ds_read_b128, wave's k-half
    const u16* Bb = Bs + (s % 3) * 8192;
#pragma unroll
    for (int j = 0; j < 4; ++j) {
      int row = wn * 64 + j * 16 + la;
      int ps = (wk * 4 + q) ^ (row & 7);
      bb[j] = *reinterpret_cast<const bf16x8*>(Bb + row * 64 + ps * 8);
    }
  };
  auto compute = [&](bf16x8 (&a)[4]) {
    if (wn == 0) {                      // rowsum: wk halves partition k
#pragma unroll
      for (int i = 0; i < 4; ++i) {
        float ls = 0.f;
#pragma unroll
        for (int e = 0; e < 8; ++e) ls += (float)a[i][e];
        lacc[i] += ls;
      }
    }
    __builtin_amdgcn_s_setprio(1);
#pragma unroll
    for (int i = 0; i < 4; ++i)
#pragma unroll
      for (int j = 0; j < 4; ++j)
        acc[i][j] = __builtin_amdgcn_mfma_f32_16x16x32_bf16(a[i], bb[j], acc[i][j], 0, 0, 0);
    __builtin_amdgcn_s_setprio(0);
  };

  // prologue: a(0) first (vmcnt ledger), then B(0), B(1)
  loadA(aA);                            // tile 0(+wk); aPtr -> step 1
  stageB(0); stageB(1);
  VMCNT(2);                             // a(0)+B(0) landed; B(1) flying
  __builtin_amdgcn_s_barrier();

  for (int s = 0; s < 30; s += 2) {
    // even step: compute aA, prefetch into aB
    loadA(aB); stageB(s + 2);
    rdB(s);
    compute(aA);
    VMCNT(2); __builtin_amdgcn_s_barrier();
    // odd step: compute aB, prefetch into aA
    loadA(aA); stageB(s + 3);
    rdB(s + 1);
    compute(aB);
    VMCNT(2); __builtin_amdgcn_s_barrier();
  }
  // s = 30: prefetch a(31) only (aPtr already at tile 31)
  loadA(aB);
  rdB(30);
  compute(aA);
  VMCNT(0); __builtin_amdgcn_s_barrier();   // a(31)+B(31) landed, all waves
  // s = 31
  rdB(31); LGKMCNT0; __builtin_amdgcn_s_barrier();  // all reads done pre-overlay
  compute(aB);

  // ---- epilogue: rowsum halves + wk-pair acc reduction via LDS ------
  float l[4];
#pragma unroll
  for (int i = 0; i < 4; ++i) {
    l[i] = lacc[i];
    l[i] += __shfl_xor(l[i], 16);
    l[i] += __shfl_xor(l[i], 32);       // sum across 4 q-lanes (la preserved)
  }
  if (wn == 0 && q == 0) {              // 2 wm x 2 wk waves x 16 la x 4 i
#pragma unroll
    for (int i = 0; i < 4; ++i) larr2[wk][wm * 64 + i * 16 + la] = l[i];
  }
  float* sp = scratch + (wid >> 1) * 4096;   // 16KB per (wm,wn) pair
  if (wk == 1) {
#pragma unroll
    for (int i = 0; i < 4; ++i)
#pragma unroll
      for (int j = 0; j < 4; ++j)
        *reinterpret_cast<f32x4*>(sp + (i * 4 + j) * 256 + lane * 4) = acc[i][j];
  }
  __syncthreads();
  if (wk == 0) {
#pragma unroll
    for (int i = 0; i < 4; ++i)
#pragma unroll
      for (int j = 0; j < 4; ++j) {
        f32x4 o = *reinterpret_cast<const f32x4*>(sp + (i * 4 + j) * 256 + lane * 4);
#pragma unroll
        for (int r = 0; r < 4; ++r) acc[i][j][r] += o[r];
      }
    float* C = out + ((size_t)b * 2048 + bm) * 512;
    const int r0 = q * 4, cn = lane & 15;
    float inv[4][4];
#pragma unroll
    for (int i = 0; i < 4; ++i)
#pragma unroll
      for (int r = 0; r < 4; ++r) {
        int row = wm * 64 + i * 16 + r0 + r;
        inv[i][r] = 1.0f / (larr2[0][row] + larr2[1][row]);
      }
#pragma unroll
    for (int i = 0; i < 4; ++i)
#pragma unroll
      for (int j = 0; j < 4; ++j)
#pragma unroll
        for (int r = 0; r < 4; ++r) {
          int m = wm * 64 + 16 * i + r0 + r;
          int n = bn + 64 * wn + 16 * j + cn;
          C[(size_t)m * 512 + n] = acc[i][j][r] * inv[i][r];
        }
  }
}

extern "C" void kernel_launch(void* const* d_in, const int* in_sizes, int n_in,
                              void* d_out, int out_size, void* d_ws, size_t ws_size,
                              hipStream_t stream) {
  const float* x  = (const float*)d_in[0];
  const float* Wq = (const float*)d_in[1];
  const float* Wk = (const float*)d_in[2];
  const float* Wv = (const float*)d_in[3];
  float* out = (float*)d_out;

  // ws layout: Xb bf16[16384][512] | Wt bf16[3][512][512] | Q | K | Vt2 | S2
  char* p = (char*)d_ws;
  u16* Xb = (u16*)p;            p += (size_t)16384 * 512 * 2;
  u16* Wt = (u16*)p;            p += (size_t)3 * 512 * 512 * 2;
  u16* Q  = (u16*)p;            p += (size_t)16384 * 512 * 2;
  u16* K  = (u16*)p;            p += (size_t)16384 * 512 * 2;
  u16* Vt2 = (u16*)p;           p += (size_t)16384 * 512 * 2;
  u16* S2 = (u16*)p;

  cast_x_kernel<<<dim3(8192), dim3(256), 0, stream>>>(x, Xb, 16384 * 512 / 4);
  transpose_w_kernel<<<dim3(16, 16, 3), dim3(32, 32), 0, stream>>>(Wq, Wk, Wv, Wt);
  qkv_kernel<<<dim3(4, 128, 3), dim3(256), 0, stream>>>(Xb, Wt, Q, K, Vt2);
  scores8_kernel<<<dim3(8, 8, 8), dim3(512), 0, stream>>>(Q, K, S2);
  pv_kernel<<<dim3(512), dim3(512), 0, stream>>>(S2, Vt2, out);
}

// Round 9
// 142.883 us; speedup vs baseline: 1.2864x; 1.2864x over previous
//
#include <hip/hip_runtime.h>

typedef __attribute__((ext_vector_type(8))) __bf16 bf16x8;
typedef __attribute__((ext_vector_type(4))) float f32x4;
typedef unsigned short u16;
typedef unsigned int u32;

#define VMCNT(n) asm volatile("s_waitcnt vmcnt(" #n ")" ::: "memory")
#define LGKMCNT0 asm volatile("s_waitcnt lgkmcnt(0)" ::: "memory")

__device__ __forceinline__ u16 f2bf(float f) {
  union { float f; u32 u; } v; v.f = f;
  u32 r = v.u + 0x7FFFu + ((v.u >> 16) & 1u);
  return (u16)(r >> 16);
}
__device__ __forceinline__ float fexp2(float x) {  // 2^x via v_exp_f32
  float r; asm("v_exp_f32 %0, %1" : "=v"(r) : "v"(x)); return r;
}

// ---------------- cast x fp32 -> bf16 (4 elems/thread) ----------------
__global__ __launch_bounds__(256) void cast_x_kernel(const float* __restrict__ x,
                                                     u16* __restrict__ xb, int n4) {
  int i = blockIdx.x * 256 + threadIdx.x;
  if (i >= n4) return;
  float4 v = reinterpret_cast<const float4*>(x)[i];
  ushort4 o;
  o.x = f2bf(v.x); o.y = f2bf(v.y); o.z = f2bf(v.z); o.w = f2bf(v.w);
  reinterpret_cast<ushort4*>(xb)[i] = o;
}

// ------- transpose weights: Wt[u][d] = W[d][u], fp32 -> bf16 ----------
__global__ __launch_bounds__(1024) void transpose_w_kernel(const float* __restrict__ Wq,
                                                           const float* __restrict__ Wk,
                                                           const float* __restrict__ Wv,
                                                           u16* __restrict__ Wt) {
  const float* src = blockIdx.z == 0 ? Wq : (blockIdx.z == 1 ? Wk : Wv);
  u16* dst = Wt + (size_t)blockIdx.z * 512 * 512;
  __shared__ float tile[32][33];
  int u0 = blockIdx.x * 32, d0 = blockIdx.y * 32;
  tile[threadIdx.y][threadIdx.x] = src[(d0 + threadIdx.y) * 512 + u0 + threadIdx.x];
  __syncthreads();
  dst[(u0 + threadIdx.y) * 512 + d0 + threadIdx.x] = f2bf(tile[threadIdx.x][threadIdx.y]);
}

// ---------------- QKV projection: 128x128 tile, ring-3 counted-vmcnt ----
// z==2 (V) writes Vt2[b][kt][u][32] (kt = s>>5): pv stages contiguous tiles.
__global__ __launch_bounds__(256) void qkv_kernel(const u16* __restrict__ Xb,
                                                  const u16* __restrict__ Wt3,
                                                  u16* __restrict__ Q, u16* __restrict__ K,
                                                  u16* __restrict__ Vt2) {
  __shared__ u16 As[3][128 * 32], Bs[3][128 * 32];
  const int bm = blockIdx.y * 128;
  const int bn = blockIdx.x * 128;
  const int z = blockIdx.z;
  const u16* A = Xb + (size_t)bm * 512;
  const u16* Bt = Wt3 + (size_t)z * 512 * 512 + (size_t)bn * 512;

  const int t = threadIdx.x;
  const int lane = t & 63;
  const int w = t >> 6;
  const int wr = w >> 1, wc = w & 1;
  const int la = lane & 15;
  const int q = lane >> 4;
  f32x4 acc[4][4] = {};

  auto stage = [&](int buf, int kt) {
    const int k0 = kt * 32;
#pragma unroll
    for (int it = 0; it < 2; ++it) {    // A: 128 rows -> 512 chunks
      int c = it * 256 + t, row = c >> 2;
      int col = ((c & 3) ^ ((row >> 1) & 3)) << 3;
      __builtin_amdgcn_global_load_lds(
          (const __attribute__((address_space(1))) void*)(A + (size_t)row * 512 + k0 + col),
          (__attribute__((address_space(3))) void*)(&As[buf][c * 8]), 16, 0, 0);
    }
#pragma unroll
    for (int it = 0; it < 2; ++it) {    // B: 128 rows -> 512 chunks
      int c = it * 256 + t, row = c >> 2;
      int col = ((c & 3) ^ ((row >> 1) & 3)) << 3;
      __builtin_amdgcn_global_load_lds(
          (const __attribute__((address_space(1))) void*)(Bt + (size_t)row * 512 + k0 + col),
          (__attribute__((address_space(3))) void*)(&Bs[buf][c * 8]), 16, 0, 0);
    }
  };

  auto body = [&](int buf) {
    bf16x8 a[4], b[4];
#pragma unroll
    for (int i = 0; i < 4; ++i) {
      int row = wr * 64 + i * 16 + la;
      a[i] = *reinterpret_cast<const bf16x8*>(&As[buf][row * 32 + ((q ^ ((row >> 1) & 3)) << 3)]);
    }
#pragma unroll
    for (int j = 0; j < 4; ++j) {
      int row = wc * 64 + j * 16 + la;
      b[j] = *reinterpret_cast<const bf16x8*>(&Bs[buf][row * 32 + ((q ^ ((row >> 1) & 3)) << 3)]);
    }
    __builtin_amdgcn_s_setprio(1);
#pragma unroll
    for (int i = 0; i < 4; ++i)
#pragma unroll
      for (int j = 0; j < 4; ++j)
        acc[i][j] = __builtin_amdgcn_mfma_f32_16x16x32_bf16(a[i], b[j], acc[i][j], 0, 0, 0);
    __builtin_amdgcn_s_setprio(0);
  };

  stage(0, 0); stage(1, 1);             // 8 loads/thread in flight
  int cb = 0, sb = 2;
  for (int kt = 0; kt < 14; ++kt) {
    VMCNT(4);                           // tile kt landed; kt+1 flying
    __builtin_amdgcn_s_barrier();       // all waves' kt landed; buf sb free
    stage(sb, kt + 2);
    body(cb);
    cb = (cb == 2) ? 0 : cb + 1;
    sb = (sb == 2) ? 0 : sb + 1;
  }
  VMCNT(4); __builtin_amdgcn_s_barrier(); body(2);   // kt=14 -> buf 14%3=2
  VMCNT(0); __builtin_amdgcn_s_barrier(); body(0);   // kt=15 -> buf 0

  const int r0 = q * 4, cn = lane & 15;
  if (z < 2) {
    u16* out = (z == 0) ? Q : K;
#pragma unroll
    for (int i = 0; i < 4; ++i)
#pragma unroll
      for (int j = 0; j < 4; ++j)
#pragma unroll
        for (int r = 0; r < 4; ++r) {
          int m = bm + 64 * wr + 16 * i + r0 + r;
          int n = bn + 64 * wc + 16 * j + cn;
          out[(size_t)m * 512 + n] = f2bf(acc[i][j][r]);
        }
  } else {
#pragma unroll
    for (int i = 0; i < 4; ++i)
#pragma unroll
      for (int j = 0; j < 4; ++j)
#pragma unroll
        for (int r = 0; r < 4; ++r) {
          int m = bm + 64 * wr + 16 * i + r0 + r;
          int u = bn + 64 * wc + 16 * j + cn;
          int b = m >> 11, s = m & 2047;
          // Vt2[b][kt=s>>5][u][s&31]
          Vt2[(((size_t)b * 64 + (s >> 5)) * 512 + u) * 32 + (s & 31)] = f2bf(acc[i][j][r]);
        }
  }
}

// ------ P = exp(Q K^T / sqrt(512)) -> bf16: 256x128 tile, ring-3 ------
// Round-8 post-mortem applied: old scores8 had acc[8][4]=128 AGPR + 48
// VGPR frags -> ~176 regs -> 2 waves/SIMD -> only ONE 8-wave block/CU
// (the latency-bound regime pv escaped in round 6 for +12%). This version
// shrinks per-wave acc to 64 AGPR (64q x 64col per wave, 8 waves = 4 wm
// x 2 wn over a 256x128 tile), frags a4+b4 = 32 VGPR (proven-fit budget),
// ring-3 LDS 72KB -> TWO blocks/CU, grid 1024 = 4/CU. 3 gload_lds per
// thread/tile -> VMCNT(3) ledger (tile kt landed, kt+1 flying).
// Output layout S2[b][kt][q][32] (kt = k>>5) unchanged.
__global__ __launch_bounds__(512, 4) void scores_kernel(const u16* __restrict__ Q,
                                                        const u16* __restrict__ K,
                                                        u16* __restrict__ S2) {
  __shared__ u16 As[3][256 * 32], Bs[3][128 * 32];
  const int id = blockIdx.x;
  const int b = id & 7;                 // batch == XCD
  const int local = id >> 3;            // 0..127
  const int qi = local & 7;             // q-tile (256 rows)
  const int ki = local >> 3;            // k-col tile (128 cols)
  const int bm = qi * 256;
  const int bn = ki * 128;
  const u16* Aq = Q + (size_t)(b * 2048 + bm) * 512;
  const u16* Bk = K + (size_t)(b * 2048 + bn) * 512;

  const int t = threadIdx.x;            // 0..511
  const int lane = t & 63;
  const int wid = t >> 6;               // 0..7
  const int wm = wid >> 1;              // 0..3: q 64-row block
  const int wn = wid & 1;               // 0..1: k-col 64 block
  const int la = lane & 15;
  const int q = lane >> 4;              // k-slot 0..3 (8 elems each)

  f32x4 acc[4][4] = {};

  auto stage = [&](int kt) {
    const int buf = kt % 3;
    const int koff = kt * 32;
#pragma unroll
    for (int it = 0; it < 2; ++it) {    // A: 256 rows -> 1024 chunks
      int c = it * 512 + t, row = c >> 2;
      int col = ((c & 3) ^ ((row >> 1) & 3)) << 3;
      __builtin_amdgcn_global_load_lds(
          (const __attribute__((address_space(1))) void*)(Aq + (size_t)row * 512 + koff + col),
          (__attribute__((address_space(3))) void*)(&As[buf][c * 8]), 16, 0, 0);
    }
    {                                   // B: 128 rows -> 512 chunks
      int c = t, row = c >> 2;
      int col = ((c & 3) ^ ((row >> 1) & 3)) << 3;
      __builtin_amdgcn_global_load_lds(
          (const __attribute__((address_space(1))) void*)(Bk + (size_t)row * 512 + koff + col),
          (__attribute__((address_space(3))) void*)(&Bs[buf][c * 8]), 16, 0, 0);
    }
  };

  auto body = [&](int kt) {
    const int buf = kt % 3;
    bf16x8 a[4], bb[4];
#pragma unroll
    for (int i = 0; i < 4; ++i) {
      int row = wm * 64 + i * 16 + la;
      a[i] = *reinterpret_cast<const bf16x8*>(&As[buf][row * 32 + ((q ^ ((row >> 1) & 3)) << 3)]);
    }
#pragma unroll
    for (int j = 0; j < 4; ++j) {
      int row = wn * 64 + j * 16 + la;
      bb[j] = *reinterpret_cast<const bf16x8*>(&Bs[buf][row * 32 + ((q ^ ((row >> 1) & 3)) << 3)]);
    }
    __builtin_amdgcn_s_setprio(1);
#pragma unroll
    for (int i = 0; i < 4; ++i)
#pragma unroll
      for (int j = 0; j < 4; ++j)
        acc[i][j] = __builtin_amdgcn_mfma_f32_16x16x32_bf16(a[i], bb[j], acc[i][j], 0, 0, 0);
    __builtin_amdgcn_s_setprio(0);
  };

  stage(0); stage(1);                   // 6 loads/thread in flight
  for (int kt = 0; kt < 14; ++kt) {
    VMCNT(3);                           // tile kt landed; kt+1 flying
    __builtin_amdgcn_s_barrier();       // all waves' kt landed; buf (kt+2)%3 free
    stage(kt + 2);
    body(kt);
  }
  VMCNT(3); __builtin_amdgcn_s_barrier(); body(14);  // buf 2
  VMCNT(0); __builtin_amdgcn_s_barrier(); body(15);  // buf 0

  const float scale = 0.06375872127f;   // log2(e)/sqrt(512)
  const int r0h = q * 4;
#pragma unroll
  for (int i = 0; i < 4; ++i)
#pragma unroll
    for (int j = 0; j < 4; ++j) {
      int n = bn + wn * 64 + j * 16;                 // k-col base (la added below)
      int kt_j = n >> 5;
      int ke_j = (n & 31) + la;                      // no carry: (n&31) in {0,16}, la<16
      u16* dst = S2 + ((size_t)(b * 64 + kt_j) * 2048) * 32 + ke_j;
#pragma unroll
      for (int r = 0; r < 4; ++r) {
        int m = bm + wm * 64 + i * 16 + r0h + r;
        dst[(size_t)m * 32] = f2bf(fexp2(acc[i][j][r] * scale));
      }
    }
}

// ---- out = (P * V) / rowsum(P): 128x128, BK=64, k-split waves, ring-2 ----
// (round-7 version, best measured: 53.5us. Round-8's A-direct double-buffer
// spilled: 64 AGPR acc + 48 frag VGPRs > the 128-reg unified budget at
// launch_bounds(512,4) -> +99MB scratch writes. Reverted.)
__global__ __launch_bounds__(512, 4) void pv_kernel(const u16* __restrict__ S2,
                                                    const u16* __restrict__ Vt2,
                                                    float* __restrict__ out) {
  __shared__ __align__(16) char smem[65536];      // As[2][8192] | Bs[2][8192] u16
  __shared__ float larr2[2][128];                 // rowsum halves (per wk)
  u16* As = (u16*)smem;                           // [2][128*64]
  u16* Bs = As + 2 * 8192;                        // [2][128*64]
  float* scratch = (float*)smem;                  // epilogue overlay (64KB)

  const int id = blockIdx.x;
  const int b = id & 7;                 // batch == XCD
  const int local = id >> 3;            // 0..63
  const int bn = (local & 3) * 128;     // u cols
  const int bm = (local >> 2) * 128;    // q rows

  // S2[b][kt][q][32]: tile base (b,kt,bm) = A2 + kt*65536 (+row*32)
  const u16* A2 = S2 + ((size_t)b * 64 * 2048 + (size_t)bm) * 32;
  // Vt2[b][kt][u][32]: tile base (b,kt,bn) = B2 + kt*16384 (+row*32)
  const u16* B2 = Vt2 + ((size_t)b * 64 * 512 + (size_t)bn) * 32;

  const int t = threadIdx.x;            // 0..511
  const int lane = t & 63;
  const int wid = t >> 6;               // 0..7
  const int wm = (wid >> 2) & 1;        // q 64-row block
  const int wn = (wid >> 1) & 1;        // u 64-col block
  const int wk = wid & 1;               // k half (32 of each BK=64)
  const int la = lane & 15;
  const int q = lane >> 4;

  f32x4 acc[4][4] = {};
  float lacc[4] = {0.f, 0.f, 0.f, 0.f};

  // stage step s = k-tiles 2s,2s+1 into buf s&1. 4 loads/thread.
  auto stage = [&](int s) {
    const int buf = s & 1;
#pragma unroll
    for (int it = 0; it < 2; ++it) {    // A: 1024 chunks
      int c = it * 512 + t;
      int row = c >> 3, pslot = c & 7;
      int lslot = pslot ^ (row & 7);
      __builtin_amdgcn_global_load_lds(
          (const __attribute__((address_space(1))) void*)(
              A2 + (size_t)(2 * s + (lslot >> 2)) * 65536 + row * 32 + (lslot & 3) * 8),
          (__attribute__((address_space(3))) void*)(As + buf * 8192 + c * 8), 16, 0, 0);
    }
#pragma unroll
    for (int it = 0; it < 2; ++it) {    // B: 1024 chunks
      int c = it * 512 + t;
      int row = c >> 3, pslot = c & 7;
      int lslot = pslot ^ (row & 7);
      __builtin_amdgcn_global_load_lds(
          (const __attribute__((address_space(1))) void*)(
              B2 + (size_t)(2 * s + (lslot >> 2)) * 16384 + row * 32 + (lslot & 3) * 8),
          (__attribute__((address_space(3))) void*)(Bs + buf * 8192 + c * 8), 16, 0, 0);
    }
  };

  bf16x8 a[4], bb[4];
  auto rd = [&](int buf) {              // 8 ds_read_b128, wave's k-half only
    const u16* Ab = As + buf * 8192;
    const u16* Bb = Bs + buf * 8192;
#pragma unroll
    for (int i = 0; i < 4; ++i) {
      int row = wm * 64 + i * 16 + la;
      int ps = (wk * 4 + q) ^ (row & 7);
      a[i] = *reinterpret_cast<const bf16x8*>(Ab + row * 64 + ps * 8);
    }
#pragma unroll
    for (int j = 0; j < 4; ++j) {
      int row = wn * 64 + j * 16 + la;
      int ps = (wk * 4 + q) ^ (row & 7);
      bb[j] = *reinterpret_cast<const bf16x8*>(Bb + row * 64 + ps * 8);
    }
  };
  auto compute = [&]() {
    if (wn == 0) {                      // rowsum: wk halves partition k
#pragma unroll
      for (int i = 0; i < 4; ++i) {
        float ls = 0.f;
#pragma unroll
        for (int e = 0; e < 8; ++e) ls += (float)a[i][e];
        lacc[i] += ls;
      }
    }
    __builtin_amdgcn_s_setprio(1);
#pragma unroll
    for (int i = 0; i < 4; ++i)
#pragma unroll
      for (int j = 0; j < 4; ++j)
        acc[i][j] = __builtin_amdgcn_mfma_f32_16x16x32_bf16(a[i], bb[j], acc[i][j], 0, 0, 0);
    __builtin_amdgcn_s_setprio(0);
  };

  stage(0); stage(1);                   // 8 loads/thread in flight
  for (int s = 0; s < 30; ++s) {
    VMCNT(4);                           // step s landed; s+1 flying
    __builtin_amdgcn_s_barrier();       // all waves see buf s&1 full
    rd(s & 1);                          // ds_reads of current buf
    LGKMCNT0;                           // my reads landed in regs
    __builtin_amdgcn_s_barrier();       // all waves' reads done -> buf free
    stage(s + 2);                       // overwrite buf s&1
    compute();
  }
  VMCNT(4); __builtin_amdgcn_s_barrier();            // step 30 (buf 0)
  rd(0); LGKMCNT0; __builtin_amdgcn_s_barrier(); compute();
  VMCNT(0); __builtin_amdgcn_s_barrier();            // step 31 (buf 1)
  rd(1); LGKMCNT0; __builtin_amdgcn_s_barrier();     // all reads done pre-overlay
  compute();

  // ---- epilogue: rowsum halves + wk-pair acc reduction via LDS ------
  float l[4];
#pragma unroll
  for (int i = 0; i < 4; ++i) {
    l[i] = lacc[i];
    l[i] += __shfl_xor(l[i], 16);
    l[i] += __shfl_xor(l[i], 32);       // sum across 4 q-lanes (la preserved)
  }
  if (wn == 0 && q == 0) {              // 2 wm x 2 wk waves x 16 la x 4 i
#pragma unroll
    for (int i = 0; i < 4; ++i) larr2[wk][wm * 64 + i * 16 + la] = l[i];
  }
  float* sp = scratch + (wid >> 1) * 4096;   // 16KB per (wm,wn) pair
  if (wk == 1) {
#pragma unroll
    for (int i = 0; i < 4; ++i)
#pragma unroll
      for (int j = 0; j < 4; ++j)
        *reinterpret_cast<f32x4*>(sp + (i * 4 + j) * 256 + lane * 4) = acc[i][j];
  }
  __syncthreads();
  if (wk == 0) {
#pragma unroll
    for (int i = 0; i < 4; ++i)
#pragma unroll
      for (int j = 0; j < 4; ++j) {
        f32x4 o = *reinterpret_cast<const f32x4*>(sp + (i * 4 + j) * 256 + lane * 4);
#pragma unroll
        for (int r = 0; r < 4; ++r) acc[i][j][r] += o[r];
      }
    float* C = out + ((size_t)b * 2048 + bm) * 512;
    const int r0 = q * 4, cn = lane & 15;
    float inv[4][4];
#pragma unroll
    for (int i = 0; i < 4; ++i)
#pragma unroll
      for (int r = 0; r < 4; ++r) {
        int row = wm * 64 + i * 16 + r0 + r;
        inv[i][r] = 1.0f / (larr2[0][row] + larr2[1][row]);
      }
#pragma unroll
    for (int i = 0; i < 4; ++i)
#pragma unroll
      for (int j = 0; j < 4; ++j)
#pragma unroll
        for (int r = 0; r < 4; ++r) {
          int m = wm * 64 + 16 * i + r0 + r;
          int n = bn + 64 * wn + 16 * j + cn;
          C[(size_t)m * 512 + n] = acc[i][j][r] * inv[i][r];
        }
  }
}

extern "C" void kernel_launch(void* const* d_in, const int* in_sizes, int n_in,
                              void* d_out, int out_size, void* d_ws, size_t ws_size,
                              hipStream_t stream) {
  const float* x  = (const float*)d_in[0];
  const float* Wq = (const float*)d_in[1];
  const float* Wk = (const float*)d_in[2];
  const float* Wv = (const float*)d_in[3];
  float* out = (float*)d_out;

  // ws layout: Xb bf16[16384][512] | Wt bf16[3][512][512] | Q | K | Vt2 | S2
  char* p = (char*)d_ws;
  u16* Xb = (u16*)p;            p += (size_t)16384 * 512 * 2;
  u16* Wt = (u16*)p;            p += (size_t)3 * 512 * 512 * 2;
  u16* Q  = (u16*)p;            p += (size_t)16384 * 512 * 2;
  u16* K  = (u16*)p;            p += (size_t)16384 * 512 * 2;
  u16* Vt2 = (u16*)p;           p += (size_t)16384 * 512 * 2;
  u16* S2 = (u16*)p;

  cast_x_kernel<<<dim3(8192), dim3(256), 0, stream>>>(x, Xb, 16384 * 512 / 4);
  transpose_w_kernel<<<dim3(16, 16, 3), dim3(32, 32), 0, stream>>>(Wq, Wk, Wv, Wt);
  qkv_kernel<<<dim3(4, 128, 3), dim3(256), 0, stream>>>(Xb, Wt, Q, K, Vt2);
  scores_kernel<<<dim3(1024), dim3(512), 0, stream>>>(Q, K, S2);
  pv_kernel<<<dim3(512), dim3(512), 0, stream>>>(S2, Vt2, out);
}

// Round 10
// 142.712 us; speedup vs baseline: 1.2879x; 1.0012x over previous
//
#include <hip/hip_runtime.h>

typedef __attribute__((ext_vector_type(8))) __bf16 bf16x8;
typedef __attribute__((ext_vector_type(4))) float f32x4;
typedef unsigned short u16;
typedef unsigned int u32;

#define VMCNT(n) asm volatile("s_waitcnt vmcnt(" #n ")" ::: "memory")
#define LGKMCNT0 asm volatile("s_waitcnt lgkmcnt(0)" ::: "memory")

__device__ __forceinline__ u16 f2bf(float f) {
  union { float f; u32 u; } v; v.f = f;
  u32 r = v.u + 0x7FFFu + ((v.u >> 16) & 1u);
  return (u16)(r >> 16);
}
__device__ __forceinline__ float fexp2(float x) {  // 2^x via v_exp_f32
  float r; asm("v_exp_f32 %0, %1" : "=v"(r) : "v"(x)); return r;
}

// ---------------- cast x fp32 -> bf16 (4 elems/thread) ----------------
__global__ __launch_bounds__(256) void cast_x_kernel(const float* __restrict__ x,
                                                     u16* __restrict__ xb, int n4) {
  int i = blockIdx.x * 256 + threadIdx.x;
  if (i >= n4) return;
  float4 v = reinterpret_cast<const float4*>(x)[i];
  ushort4 o;
  o.x = f2bf(v.x); o.y = f2bf(v.y); o.z = f2bf(v.z); o.w = f2bf(v.w);
  reinterpret_cast<ushort4*>(xb)[i] = o;
}

// ------- transpose weights: Wt[u][d] = W[d][u], fp32 -> bf16 ----------
__global__ __launch_bounds__(1024) void transpose_w_kernel(const float* __restrict__ Wq,
                                                           const float* __restrict__ Wk,
                                                           const float* __restrict__ Wv,
                                                           u16* __restrict__ Wt) {
  const float* src = blockIdx.z == 0 ? Wq : (blockIdx.z == 1 ? Wk : Wv);
  u16* dst = Wt + (size_t)blockIdx.z * 512 * 512;
  __shared__ float tile[32][33];
  int u0 = blockIdx.x * 32, d0 = blockIdx.y * 32;
  tile[threadIdx.y][threadIdx.x] = src[(d0 + threadIdx.y) * 512 + u0 + threadIdx.x];
  __syncthreads();
  dst[(u0 + threadIdx.y) * 512 + d0 + threadIdx.x] = f2bf(tile[threadIdx.x][threadIdx.y]);
}

// ---------------- QKV projection: 128x128 tile, ring-3 counted-vmcnt ----
// z==2 (V) writes Vt2[b][kt][u][32] (kt = s>>5): pv stages contiguous tiles.
__global__ __launch_bounds__(256) void qkv_kernel(const u16* __restrict__ Xb,
                                                  const u16* __restrict__ Wt3,
                                                  u16* __restrict__ Q, u16* __restrict__ K,
                                                  u16* __restrict__ Vt2) {
  __shared__ u16 As[3][128 * 32], Bs[3][128 * 32];
  const int bm = blockIdx.y * 128;
  const int bn = blockIdx.x * 128;
  const int z = blockIdx.z;
  const u16* A = Xb + (size_t)bm * 512;
  const u16* Bt = Wt3 + (size_t)z * 512 * 512 + (size_t)bn * 512;

  const int t = threadIdx.x;
  const int lane = t & 63;
  const int w = t >> 6;
  const int wr = w >> 1, wc = w & 1;
  const int la = lane & 15;
  const int q = lane >> 4;
  f32x4 acc[4][4] = {};

  auto stage = [&](int buf, int kt) {
    const int k0 = kt * 32;
#pragma unroll
    for (int it = 0; it < 2; ++it) {    // A: 128 rows -> 512 chunks
      int c = it * 256 + t, row = c >> 2;
      int col = ((c & 3) ^ ((row >> 1) & 3)) << 3;
      __builtin_amdgcn_global_load_lds(
          (const __attribute__((address_space(1))) void*)(A + (size_t)row * 512 + k0 + col),
          (__attribute__((address_space(3))) void*)(&As[buf][c * 8]), 16, 0, 0);
    }
#pragma unroll
    for (int it = 0; it < 2; ++it) {    // B: 128 rows -> 512 chunks
      int c = it * 256 + t, row = c >> 2;
      int col = ((c & 3) ^ ((row >> 1) & 3)) << 3;
      __builtin_amdgcn_global_load_lds(
          (const __attribute__((address_space(1))) void*)(Bt + (size_t)row * 512 + k0 + col),
          (__attribute__((address_space(3))) void*)(&Bs[buf][c * 8]), 16, 0, 0);
    }
  };

  auto body = [&](int buf) {
    bf16x8 a[4], b[4];
#pragma unroll
    for (int i = 0; i < 4; ++i) {
      int row = wr * 64 + i * 16 + la;
      a[i] = *reinterpret_cast<const bf16x8*>(&As[buf][row * 32 + ((q ^ ((row >> 1) & 3)) << 3)]);
    }
#pragma unroll
    for (int j = 0; j < 4; ++j) {
      int row = wc * 64 + j * 16 + la;
      b[j] = *reinterpret_cast<const bf16x8*>(&Bs[buf][row * 32 + ((q ^ ((row >> 1) & 3)) << 3)]);
    }
    __builtin_amdgcn_s_setprio(1);
#pragma unroll
    for (int i = 0; i < 4; ++i)
#pragma unroll
      for (int j = 0; j < 4; ++j)
        acc[i][j] = __builtin_amdgcn_mfma_f32_16x16x32_bf16(a[i], b[j], acc[i][j], 0, 0, 0);
    __builtin_amdgcn_s_setprio(0);
  };

  stage(0, 0); stage(1, 1);             // 8 loads/thread in flight
  int cb = 0, sb = 2;
  for (int kt = 0; kt < 14; ++kt) {
    VMCNT(4);                           // tile kt landed; kt+1 flying
    __builtin_amdgcn_s_barrier();       // all waves' kt landed; buf sb free
    stage(sb, kt + 2);
    body(cb);
    cb = (cb == 2) ? 0 : cb + 1;
    sb = (sb == 2) ? 0 : sb + 1;
  }
  VMCNT(4); __builtin_amdgcn_s_barrier(); body(2);   // kt=14 -> buf 14%3=2
  VMCNT(0); __builtin_amdgcn_s_barrier(); body(0);   // kt=15 -> buf 0

  const int r0 = q * 4, cn = lane & 15;
  if (z < 2) {
    u16* out = (z == 0) ? Q : K;
#pragma unroll
    for (int i = 0; i < 4; ++i)
#pragma unroll
      for (int j = 0; j < 4; ++j)
#pragma unroll
        for (int r = 0; r < 4; ++r) {
          int m = bm + 64 * wr + 16 * i + r0 + r;
          int n = bn + 64 * wc + 16 * j + cn;
          out[(size_t)m * 512 + n] = f2bf(acc[i][j][r]);
        }
  } else {
#pragma unroll
    for (int i = 0; i < 4; ++i)
#pragma unroll
      for (int j = 0; j < 4; ++j)
#pragma unroll
        for (int r = 0; r < 4; ++r) {
          int m = bm + 64 * wr + 16 * i + r0 + r;
          int u = bn + 64 * wc + 16 * j + cn;
          int b = m >> 11, s = m & 2047;
          // Vt2[b][kt=s>>5][u][s&31]
          Vt2[(((size_t)b * 64 + (s >> 5)) * 512 + u) * 32 + (s & 31)] = f2bf(acc[i][j][r]);
        }
  }
}

// ------ P = exp(Q K^T / sqrt(512)) -> bf16: 256x128 tile, ring-3 ------
// Round-8 post-mortem applied: old scores8 had acc[8][4]=128 AGPR + 48
// VGPR frags -> ~176 regs -> 2 waves/SIMD -> only ONE 8-wave block/CU
// (the latency-bound regime pv escaped in round 6 for +12%). This version
// shrinks per-wave acc to 64 AGPR (64q x 64col per wave, 8 waves = 4 wm
// x 2 wn over a 256x128 tile), frags a4+b4 = 32 VGPR (proven-fit budget),
// ring-3 LDS 72KB -> TWO blocks/CU, grid 1024 = 4/CU. 3 gload_lds per
// thread/tile -> VMCNT(3) ledger (tile kt landed, kt+1 flying).
// Output layout S2[b][kt][q][32] (kt = k>>5) unchanged.
__global__ __launch_bounds__(512, 4) void scores_kernel(const u16* __restrict__ Q,
                                                        const u16* __restrict__ K,
                                                        u16* __restrict__ S2) {
  __shared__ u16 As[3][256 * 32], Bs[3][128 * 32];
  const int id = blockIdx.x;
  const int b = id & 7;                 // batch == XCD
  const int local = id >> 3;            // 0..127
  const int qi = local & 7;             // q-tile (256 rows)
  const int ki = local >> 3;            // k-col tile (128 cols)
  const int bm = qi * 256;
  const int bn = ki * 128;
  const u16* Aq = Q + (size_t)(b * 2048 + bm) * 512;
  const u16* Bk = K + (size_t)(b * 2048 + bn) * 512;

  const int t = threadIdx.x;            // 0..511
  const int lane = t & 63;
  const int wid = t >> 6;               // 0..7
  const int wm = wid >> 1;              // 0..3: q 64-row block
  const int wn = wid & 1;               // 0..1: k-col 64 block
  const int la = lane & 15;
  const int q = lane >> 4;              // k-slot 0..3 (8 elems each)

  f32x4 acc[4][4] = {};

  auto stage = [&](int kt) {
    const int buf = kt % 3;
    const int koff = kt * 32;
#pragma unroll
    for (int it = 0; it < 2; ++it) {    // A: 256 rows -> 1024 chunks
      int c = it * 512 + t, row = c >> 2;
      int col = ((c & 3) ^ ((row >> 1) & 3)) << 3;
      __builtin_amdgcn_global_load_lds(
          (const __attribute__((address_space(1))) void*)(Aq + (size_t)row * 512 + koff + col),
          (__attribute__((address_space(3))) void*)(&As[buf][c * 8]), 16, 0, 0);
    }
    {                                   // B: 128 rows -> 512 chunks
      int c = t, row = c >> 2;
      int col = ((c & 3) ^ ((row >> 1) & 3)) << 3;
      __builtin_amdgcn_global_load_lds(
          (const __attribute__((address_space(1))) void*)(Bk + (size_t)row * 512 + koff + col),
          (__attribute__((address_space(3))) void*)(&Bs[buf][c * 8]), 16, 0, 0);
    }
  };

  auto body = [&](int kt) {
    const int buf = kt % 3;
    bf16x8 a[4], bb[4];
#pragma unroll
    for (int i = 0; i < 4; ++i) {
      int row = wm * 64 + i * 16 + la;
      a[i] = *reinterpret_cast<const bf16x8*>(&As[buf][row * 32 + ((q ^ ((row >> 1) & 3)) << 3)]);
    }
#pragma unroll
    for (int j = 0; j < 4; ++j) {
      int row = wn * 64 + j * 16 + la;
      bb[j] = *reinterpret_cast<const bf16x8*>(&Bs[buf][row * 32 + ((q ^ ((row >> 1) & 3)) << 3)]);
    }
    __builtin_amdgcn_s_setprio(1);
#pragma unroll
    for (int i = 0; i < 4; ++i)
#pragma unroll
      for (int j = 0; j < 4; ++j)
        acc[i][j] = __builtin_amdgcn_mfma_f32_16x16x32_bf16(a[i], bb[j], acc[i][j], 0, 0, 0);
    __builtin_amdgcn_s_setprio(0);
  };

  stage(0); stage(1);                   // 6 loads/thread in flight
  for (int kt = 0; kt < 14; ++kt) {
    VMCNT(3);                           // tile kt landed; kt+1 flying
    __builtin_amdgcn_s_barrier();       // all waves' kt landed; buf (kt+2)%3 free
    stage(kt + 2);
    body(kt);
  }
  VMCNT(3); __builtin_amdgcn_s_barrier(); body(14);  // buf 2
  VMCNT(0); __builtin_amdgcn_s_barrier(); body(15);  // buf 0

  const float scale = 0.06375872127f;   // log2(e)/sqrt(512)
  const int r0h = q * 4;
#pragma unroll
  for (int i = 0; i < 4; ++i)
#pragma unroll
    for (int j = 0; j < 4; ++j) {
      int n = bn + wn * 64 + j * 16;                 // k-col base (la added below)
      int kt_j = n >> 5;
      int ke_j = (n & 31) + la;                      // no carry: (n&31) in {0,16}, la<16
      u16* dst = S2 + ((size_t)(b * 64 + kt_j) * 2048) * 32 + ke_j;
#pragma unroll
      for (int r = 0; r < 4; ++r) {
        int m = bm + wm * 64 + i * 16 + r0h + r;
        dst[(size_t)m * 32] = f2bf(fexp2(acc[i][j][r] * scale));
      }
    }
}

// ---- out = (P * V) / rowsum(P): 128x128, BK=64, k-split waves, ring-2 ----
// (round-7 version, best measured: 53.5us. Round-8's A-direct double-buffer
// spilled: 64 AGPR acc + 48 frag VGPRs > the 128-reg unified budget at
// launch_bounds(512,4) -> +99MB scratch writes. Reverted.)
__global__ __launch_bounds__(512, 4) void pv_kernel(const u16* __restrict__ S2,
                                                    const u16* __restrict__ Vt2,
                                                    float* __restrict__ out) {
  __shared__ __align__(16) char smem[65536];      // As[2][8192] | Bs[2][8192] u16
  __shared__ float larr2[2][128];                 // rowsum halves (per wk)
  u16* As = (u16*)smem;                           // [2][128*64]
  u16* Bs = As + 2 * 8192;                        // [2][128*64]
  float* scratch = (float*)smem;                  // epilogue overlay (64KB)

  const int id = blockIdx.x;
  const int b = id & 7;                 // batch == XCD
  const int local = id >> 3;            // 0..63
  const int bn = (local & 3) * 128;     // u cols
  const int bm = (local >> 2) * 128;    // q rows

  // S2[b][kt][q][32]: tile base (b,kt,bm) = A2 + kt*65536 (+row*32)
  const u16* A2 = S2 + ((size_t)b * 64 * 2048 + (size_t)bm) * 32;
  // Vt2[b][kt][u][32]: tile base (b,kt,bn) = B2 + kt*16384 (+row*32)
  const u16* B2 = Vt2 + ((size_t)b * 64 * 512 + (size_t)bn) * 32;

  const int t = threadIdx.x;            // 0..511
  const int lane = t & 63;
  const int wid = t >> 6;               // 0..7
  const int wm = (wid >> 2) & 1;        // q 64-row block
  const int wn = (wid >> 1) & 1;        // u 64-col block
  const int wk = wid & 1;               // k half (32 of each BK=64)
  const int la = lane & 15;
  const int q = lane >> 4;

  f32x4 acc[4][4] = {};
  float lacc[4] = {0.f, 0.f, 0.f, 0.f};

  // stage step s = k-tiles 2s,2s+1 into buf s&1. 4 loads/thread.
  auto stage = [&](int s) {
    const int buf = s & 1;
#pragma unroll
    for (int it = 0; it < 2; ++it) {    // A: 1024 chunks
      int c = it * 512 + t;
      int row = c >> 3, pslot = c & 7;
      int lslot = pslot ^ (row & 7);
      __builtin_amdgcn_global_load_lds(
          (const __attribute__((address_space(1))) void*)(
              A2 + (size_t)(2 * s + (lslot >> 2)) * 65536 + row * 32 + (lslot & 3) * 8),
          (__attribute__((address_space(3))) void*)(As + buf * 8192 + c * 8), 16, 0, 0);
    }
#pragma unroll
    for (int it = 0; it < 2; ++it) {    // B: 1024 chunks
      int c = it * 512 + t;
      int row = c >> 3, pslot = c & 7;
      int lslot = pslot ^ (row & 7);
      __builtin_amdgcn_global_load_lds(
          (const __attribute__((address_space(1))) void*)(
              B2 + (size_t)(2 * s + (lslot >> 2)) * 16384 + row * 32 + (lslot & 3) * 8),
          (__attribute__((address_space(3))) void*)(Bs + buf * 8192 + c * 8), 16, 0, 0);
    }
  };

  bf16x8 a[4], bb[4];
  auto rd = [&](int buf) {              // 8 ds_read_b128, wave's k-half only
    const u16* Ab = As + buf * 8192;
    const u16* Bb = Bs + buf * 8192;
#pragma unroll
    for (int i = 0; i < 4; ++i) {
      int row = wm * 64 + i * 16 + la;
      int ps = (wk * 4 + q) ^ (row & 7);
      a[i] = *reinterpret_cast<const bf16x8*>(Ab + row * 64 + ps * 8);
    }
#pragma unroll
    for (int j = 0; j < 4; ++j) {
      int row = wn * 64 + j * 16 + la;
      int ps = (wk * 4 + q) ^ (row & 7);
      bb[j] = *reinterpret_cast<const bf16x8*>(Bb + row * 64 + ps * 8);
    }
  };
  auto compute = [&]() {
    if (wn == 0) {                      // rowsum: wk halves partition k
#pragma unroll
      for (int i = 0; i < 4; ++i) {
        float ls = 0.f;
#pragma unroll
        for (int e = 0; e < 8; ++e) ls += (float)a[i][e];
        lacc[i] += ls;
      }
    }
    __builtin_amdgcn_s_setprio(1);
#pragma unroll
    for (int i = 0; i < 4; ++i)
#pragma unroll
      for (int j = 0; j < 4; ++j)
        acc[i][j] = __builtin_amdgcn_mfma_f32_16x16x32_bf16(a[i], bb[j], acc[i][j], 0, 0, 0);
    __builtin_amdgcn_s_setprio(0);
  };

  stage(0); stage(1);                   // 8 loads/thread in flight
  for (int s = 0; s < 30; ++s) {
    VMCNT(4);                           // step s landed; s+1 flying
    __builtin_amdgcn_s_barrier();       // all waves see buf s&1 full
    rd(s & 1);                          // ds_reads of current buf
    LGKMCNT0;                           // my reads landed in regs
    __builtin_amdgcn_s_barrier();       // all waves' reads done -> buf free
    stage(s + 2);                       // overwrite buf s&1
    compute();
  }
  VMCNT(4); __builtin_amdgcn_s_barrier();            // step 30 (buf 0)
  rd(0); LGKMCNT0; __builtin_amdgcn_s_barrier(); compute();
  VMCNT(0); __builtin_amdgcn_s_barrier();            // step 31 (buf 1)
  rd(1); LGKMCNT0; __builtin_amdgcn_s_barrier();     // all reads done pre-overlay
  compute();

  // ---- epilogue: rowsum halves + wk-pair acc reduction via LDS ------
  float l[4];
#pragma unroll
  for (int i = 0; i < 4; ++i) {
    l[i] = lacc[i];
    l[i] += __shfl_xor(l[i], 16);
    l[i] += __shfl_xor(l[i], 32);       // sum across 4 q-lanes (la preserved)
  }
  if (wn == 0 && q == 0) {              // 2 wm x 2 wk waves x 16 la x 4 i
#pragma unroll
    for (int i = 0; i < 4; ++i) larr2[wk][wm * 64 + i * 16 + la] = l[i];
  }
  float* sp = scratch + (wid >> 1) * 4096;   // 16KB per (wm,wn) pair
  if (wk == 1) {
#pragma unroll
    for (int i = 0; i < 4; ++i)
#pragma unroll
      for (int j = 0; j < 4; ++j)
        *reinterpret_cast<f32x4*>(sp + (i * 4 + j) * 256 + lane * 4) = acc[i][j];
  }
  __syncthreads();
  if (wk == 0) {
#pragma unroll
    for (int i = 0; i < 4; ++i)
#pragma unroll
      for (int j = 0; j < 4; ++j) {
        f32x4 o = *reinterpret_cast<const f32x4*>(sp + (i * 4 + j) * 256 + lane * 4);
#pragma unroll
        for (int r = 0; r < 4; ++r) acc[i][j][r] += o[r];
      }
    float* C = out + ((size_t)b * 2048 + bm) * 512;
    const int r0 = q * 4, cn = lane & 15;
    float inv[4][4];
#pragma unroll
    for (int i = 0; i < 4; ++i)
#pragma unroll
      for (int r = 0; r < 4; ++r) {
        int row = wm * 64 + i * 16 + r0 + r;
        inv[i][r] = 1.0f / (larr2[0][row] + larr2[1][row]);
      }
#pragma unroll
    for (int i = 0; i < 4; ++i)
#pragma unroll
      for (int j = 0; j < 4; ++j)
#pragma unroll
        for (int r = 0; r < 4; ++r) {
          int m = wm * 64 + 16 * i + r0 + r;
          int n = bn + 64 * wn + 16 * j + cn;
          C[(size_t)m * 512 + n] = acc[i][j][r] * inv[i][r];
        }
  }
}

extern "C" void kernel_launch(void* const* d_in, const int* in_sizes, int n_in,
                              void* d_out, int out_size, void* d_ws, size_t ws_size,
                              hipStream_t stream) {
  const float* x  = (const float*)d_in[0];
  const float* Wq = (const float*)d_in[1];
  const float* Wk = (const float*)d_in[2];
  const float* Wv = (const float*)d_in[3];
  float* out = (float*)d_out;

  // ws layout: Xb bf16[16384][512] | Wt bf16[3][512][512] | Q | K | Vt2 | S2
  char* p = (char*)d_ws;
  u16* Xb = (u16*)p;            p += (size_t)16384 * 512 * 2;
  u16* Wt = (u16*)p;            p += (size_t)3 * 512 * 512 * 2;
  u16* Q  = (u16*)p;            p += (size_t)16384 * 512 * 2;
  u16* K  = (u16*)p;            p += (size_t)16384 * 512 * 2;
  u16* Vt2 = (u16*)p;           p += (size_t)16384 * 512 * 2;
  u16* S2 = (u16*)p;

  cast_x_kernel<<<dim3(8192), dim3(256), 0, stream>>>(x, Xb, 16384 * 512 / 4);
  transpose_w_kernel<<<dim3(16, 16, 3), dim3(32, 32), 0, stream>>>(Wq, Wk, Wv, Wt);
  qkv_kernel<<<dim3(4, 128, 3), dim3(256), 0, stream>>>(Xb, Wt, Q, K, Vt2);
  scores_kernel<<<dim3(1024), dim3(512), 0, stream>>>(Q, K, S2);
  pv_kernel<<<dim3(512), dim3(512), 0, stream>>>(S2, Vt2, out);
}

// Round 11
// 138.229 us; speedup vs baseline: 1.3297x; 1.0324x over previous
//
#include <hip/hip_runtime.h>

typedef __attribute__((ext_vector_type(8))) __bf16 bf16x8;
typedef __attribute__((ext_vector_type(4))) float f32x4;
typedef unsigned short u16;
typedef unsigned int u32;

#define VMCNT(n) asm volatile("s_waitcnt vmcnt(" #n ")" ::: "memory")
#define LGKMCNT0 asm volatile("s_waitcnt lgkmcnt(0)" ::: "memory")

__device__ __forceinline__ u16 f2bf(float f) {
  union { float f; u32 u; } v; v.f = f;
  u32 r = v.u + 0x7FFFu + ((v.u >> 16) & 1u);
  return (u16)(r >> 16);
}
__device__ __forceinline__ float fexp2(float x) {  // 2^x via v_exp_f32
  float r; asm("v_exp_f32 %0, %1" : "=v"(r) : "v"(x)); return r;
}

// ---------------- cast x fp32 -> bf16 (4 elems/thread) ----------------
__global__ __launch_bounds__(256) void cast_x_kernel(const float* __restrict__ x,
                                                     u16* __restrict__ xb, int n4) {
  int i = blockIdx.x * 256 + threadIdx.x;
  if (i >= n4) return;
  float4 v = reinterpret_cast<const float4*>(x)[i];
  ushort4 o;
  o.x = f2bf(v.x); o.y = f2bf(v.y); o.z = f2bf(v.z); o.w = f2bf(v.w);
  reinterpret_cast<ushort4*>(xb)[i] = o;
}

// ------- transpose weights: Wt[u][d] = W[d][u], fp32 -> bf16 ----------
__global__ __launch_bounds__(1024) void transpose_w_kernel(const float* __restrict__ Wq,
                                                           const float* __restrict__ Wk,
                                                           const float* __restrict__ Wv,
                                                           u16* __restrict__ Wt) {
  const float* src = blockIdx.z == 0 ? Wq : (blockIdx.z == 1 ? Wk : Wv);
  u16* dst = Wt + (size_t)blockIdx.z * 512 * 512;
  __shared__ float tile[32][33];
  int u0 = blockIdx.x * 32, d0 = blockIdx.y * 32;
  tile[threadIdx.y][threadIdx.x] = src[(d0 + threadIdx.y) * 512 + u0 + threadIdx.x];
  __syncthreads();
  dst[(u0 + threadIdx.y) * 512 + d0 + threadIdx.x] = f2bf(tile[threadIdx.x][threadIdx.y]);
}

// ---------------- QKV projection: 128x128 tile, ring-3 counted-vmcnt ----
// z==2 (V) writes Vt2[b][kt][u][32] (kt = s>>5): pv stages contiguous tiles.
__global__ __launch_bounds__(256) void qkv_kernel(const u16* __restrict__ Xb,
                                                  const u16* __restrict__ Wt3,
                                                  u16* __restrict__ Q, u16* __restrict__ K,
                                                  u16* __restrict__ Vt2) {
  __shared__ u16 As[3][128 * 32], Bs[3][128 * 32];
  const int bm = blockIdx.y * 128;
  const int bn = blockIdx.x * 128;
  const int z = blockIdx.z;
  const u16* A = Xb + (size_t)bm * 512;
  const u16* Bt = Wt3 + (size_t)z * 512 * 512 + (size_t)bn * 512;

  const int t = threadIdx.x;
  const int lane = t & 63;
  const int w = t >> 6;
  const int wr = w >> 1, wc = w & 1;
  const int la = lane & 15;
  const int q = lane >> 4;
  f32x4 acc[4][4] = {};

  auto stage = [&](int buf, int kt) {
    const int k0 = kt * 32;
#pragma unroll
    for (int it = 0; it < 2; ++it) {    // A: 128 rows -> 512 chunks
      int c = it * 256 + t, row = c >> 2;
      int col = ((c & 3) ^ ((row >> 1) & 3)) << 3;
      __builtin_amdgcn_global_load_lds(
          (const __attribute__((address_space(1))) void*)(A + (size_t)row * 512 + k0 + col),
          (__attribute__((address_space(3))) void*)(&As[buf][c * 8]), 16, 0, 0);
    }
#pragma unroll
    for (int it = 0; it < 2; ++it) {    // B: 128 rows -> 512 chunks
      int c = it * 256 + t, row = c >> 2;
      int col = ((c & 3) ^ ((row >> 1) & 3)) << 3;
      __builtin_amdgcn_global_load_lds(
          (const __attribute__((address_space(1))) void*)(Bt + (size_t)row * 512 + k0 + col),
          (__attribute__((address_space(3))) void*)(&Bs[buf][c * 8]), 16, 0, 0);
    }
  };

  auto body = [&](int buf) {
    bf16x8 a[4], b[4];
#pragma unroll
    for (int i = 0; i < 4; ++i) {
      int row = wr * 64 + i * 16 + la;
      a[i] = *reinterpret_cast<const bf16x8*>(&As[buf][row * 32 + ((q ^ ((row >> 1) & 3)) << 3)]);
    }
#pragma unroll
    for (int j = 0; j < 4; ++j) {
      int row = wc * 64 + j * 16 + la;
      b[j] = *reinterpret_cast<const bf16x8*>(&Bs[buf][row * 32 + ((q ^ ((row >> 1) & 3)) << 3)]);
    }
    __builtin_amdgcn_s_setprio(1);
#pragma unroll
    for (int i = 0; i < 4; ++i)
#pragma unroll
      for (int j = 0; j < 4; ++j)
        acc[i][j] = __builtin_amdgcn_mfma_f32_16x16x32_bf16(a[i], b[j], acc[i][j], 0, 0, 0);
    __builtin_amdgcn_s_setprio(0);
  };

  stage(0, 0); stage(1, 1);             // 8 loads/thread in flight
  int cb = 0, sb = 2;
  for (int kt = 0; kt < 14; ++kt) {
    VMCNT(4);                           // tile kt landed; kt+1 flying
    __builtin_amdgcn_s_barrier();       // all waves' kt landed; buf sb free
    stage(sb, kt + 2);
    body(cb);
    cb = (cb == 2) ? 0 : cb + 1;
    sb = (sb == 2) ? 0 : sb + 1;
  }
  VMCNT(4); __builtin_amdgcn_s_barrier(); body(2);   // kt=14 -> buf 14%3=2
  VMCNT(0); __builtin_amdgcn_s_barrier(); body(0);   // kt=15 -> buf 0

  const int r0 = q * 4, cn = lane & 15;
  if (z < 2) {
    u16* out = (z == 0) ? Q : K;
#pragma unroll
    for (int i = 0; i < 4; ++i)
#pragma unroll
      for (int j = 0; j < 4; ++j)
#pragma unroll
        for (int r = 0; r < 4; ++r) {
          int m = bm + 64 * wr + 16 * i + r0 + r;
          int n = bn + 64 * wc + 16 * j + cn;
          out[(size_t)m * 512 + n] = f2bf(acc[i][j][r]);
        }
  } else {
#pragma unroll
    for (int i = 0; i < 4; ++i)
#pragma unroll
      for (int j = 0; j < 4; ++j)
#pragma unroll
        for (int r = 0; r < 4; ++r) {
          int m = bm + 64 * wr + 16 * i + r0 + r;
          int u = bn + 64 * wc + 16 * j + cn;
          int b = m >> 11, s = m & 2047;
          // Vt2[b][kt=s>>5][u][s&31]
          Vt2[(((size_t)b * 64 + (s >> 5)) * 512 + u) * 32 + (s & 31)] = f2bf(acc[i][j][r]);
        }
  }
}

// ------ P = exp(Q K^T / sqrt(512)) -> bf16: 256x256, 16 WAVES, ring-3 ------
// Round-10 post-mortem: 256x128 tile fixed regs but raised staged-bytes/
// output 1.5x -> net loss. This version keeps 256x256 (round-7's proven
// 2 loads/thread/tile ratio) but splits it over 16 waves (1024 thr), each
// 64q x 64k: acc[4][4]=64 AGPR + 32 frag VGPR ~= 116 regs < 128 -> 4
// waves/SIMD -> 16 waves/CU resident (2x round-7's reg-capped 8; m69:
// waves halve at 64/128/256 regs). Ring-3 96KB (1 block/CU), single
// barrier per step (qkv-proven ordering), VMCNT(2) ledger (2 loads/
// thread/tile, 1-deep prefetch). S2[b][kt][q][32] layout unchanged.
__global__ __launch_bounds__(1024, 4) void scores_kernel(const u16* __restrict__ Q,
                                                         const u16* __restrict__ K,
                                                         u16* __restrict__ S2) {
  __shared__ u16 ring[3][2][256 * 32];  // [buf][A=0/B=1][256 rows][32 k]
  const int bb = blockIdx.x;            // batch -> XCD
  const int bm = blockIdx.y * 256;
  const int bn = blockIdx.z * 256;
  const u16* Aq = Q + (size_t)(bb * 2048 + bm) * 512;
  const u16* Bk = K + (size_t)(bb * 2048 + bn) * 512;

  const int t = threadIdx.x;            // 0..1023
  const int lane = t & 63;
  const int wid = t >> 6;               // 0..15
  const int wm = wid >> 2;              // 0..3: q 64-row block
  const int wn = wid & 3;               // 0..3: k-col 64 block
  const int la = lane & 15;
  const int q = lane >> 4;              // k-slot 0..3 (8 elems each)

  f32x4 acc[4][4] = {};

  auto stage = [&](int kt) {
    const int buf = kt % 3;
    const int koff = kt * 32;
    {                                   // A: 256 rows -> 1024 chunks, 1/thread
      int c = t, row = c >> 2;
      int col = ((c & 3) ^ ((row >> 1) & 3)) << 3;   // inverse swizzle on source
      __builtin_amdgcn_global_load_lds(
          (const __attribute__((address_space(1))) void*)(Aq + (size_t)row * 512 + koff + col),
          (__attribute__((address_space(3))) void*)(&ring[buf][0][c * 8]), 16, 0, 0);
      __builtin_amdgcn_global_load_lds(
          (const __attribute__((address_space(1))) void*)(Bk + (size_t)row * 512 + koff + col),
          (__attribute__((address_space(3))) void*)(&ring[buf][1][c * 8]), 16, 0, 0);
    }
  };

  auto body = [&](int kt) {
    const int buf = kt % 3;
    const u16* At = ring[buf][0];
    const u16* Bt = ring[buf][1];
    bf16x8 a[4], b[4];
#pragma unroll
    for (int i = 0; i < 4; ++i) {
      int row = wm * 64 + i * 16 + la;
      a[i] = *reinterpret_cast<const bf16x8*>(At + row * 32 + ((q ^ ((row >> 1) & 3)) << 3));
    }
#pragma unroll
    for (int j = 0; j < 4; ++j) {
      int row = wn * 64 + j * 16 + la;
      b[j] = *reinterpret_cast<const bf16x8*>(Bt + row * 32 + ((q ^ ((row >> 1) & 3)) << 3));
    }
    __builtin_amdgcn_s_setprio(1);
#pragma unroll
    for (int i = 0; i < 4; ++i)
#pragma unroll
      for (int j = 0; j < 4; ++j)
        acc[i][j] = __builtin_amdgcn_mfma_f32_16x16x32_bf16(a[i], b[j], acc[i][j], 0, 0, 0);
    __builtin_amdgcn_s_setprio(0);
  };

  stage(0); stage(1);                   // 4 loads/thread in flight
  for (int kt = 0; kt < 14; ++kt) {
    VMCNT(2);                           // tile kt landed; kt+1 flying
    __builtin_amdgcn_s_barrier();       // all waves' kt landed; buf (kt+2)%3 free
    stage(kt + 2);
    body(kt);
  }
  VMCNT(2); __builtin_amdgcn_s_barrier(); body(14);  // buf 2
  VMCNT(0); __builtin_amdgcn_s_barrier(); body(15);  // buf 0

  const float scale = 0.06375872127f;   // log2(e)/sqrt(512)
  const int r0h = q * 4;
#pragma unroll
  for (int i = 0; i < 4; ++i)
#pragma unroll
    for (int j = 0; j < 4; ++j) {
      int n = bn + wn * 64 + j * 16;                 // k-col base (la added below)
      int kt_j = n >> 5;
      int ke_j = (n & 31) + la;                      // no carry: (n&31) in {0,16}, la<16
      u16* dst = S2 + ((size_t)(bb * 64 + kt_j) * 2048) * 32 + ke_j;
#pragma unroll
      for (int r = 0; r < 4; ++r) {
        int m = bm + wm * 64 + i * 16 + r0h + r;
        dst[(size_t)m * 32] = f2bf(fexp2(acc[i][j][r] * scale));
      }
    }
}

// ---- out = (P * V) / rowsum(P): 128x128, BK=64, k-split waves, ring-2 ----
// (round-7 version, best measured: 53.0us.)
__global__ __launch_bounds__(512, 4) void pv_kernel(const u16* __restrict__ S2,
                                                    const u16* __restrict__ Vt2,
                                                    float* __restrict__ out) {
  __shared__ __align__(16) char smem[65536];      // As[2][8192] | Bs[2][8192] u16
  __shared__ float larr2[2][128];                 // rowsum halves (per wk)
  u16* As = (u16*)smem;                           // [2][128*64]
  u16* Bs = As + 2 * 8192;                        // [2][128*64]
  float* scratch = (float*)smem;                  // epilogue overlay (64KB)

  const int id = blockIdx.x;
  const int b = id & 7;                 // batch == XCD
  const int local = id >> 3;            // 0..63
  const int bn = (local & 3) * 128;     // u cols
  const int bm = (local >> 2) * 128;    // q rows

  // S2[b][kt][q][32]: tile base (b,kt,bm) = A2 + kt*65536 (+row*32)
  const u16* A2 = S2 + ((size_t)b * 64 * 2048 + (size_t)bm) * 32;
  // Vt2[b][kt][u][32]: tile base (b,kt,bn) = B2 + kt*16384 (+row*32)
  const u16* B2 = Vt2 + ((size_t)b * 64 * 512 + (size_t)bn) * 32;

  const int t = threadIdx.x;            // 0..511
  const int lane = t & 63;
  const int wid = t >> 6;               // 0..7
  const int wm = (wid >> 2) & 1;        // q 64-row block
  const int wn = (wid >> 1) & 1;        // u 64-col block
  const int wk = wid & 1;               // k half (32 of each BK=64)
  const int la = lane & 15;
  const int q = lane >> 4;

  f32x4 acc[4][4] = {};
  float lacc[4] = {0.f, 0.f, 0.f, 0.f};

  // stage step s = k-tiles 2s,2s+1 into buf s&1. 4 loads/thread.
  auto stage = [&](int s) {
    const int buf = s & 1;
#pragma unroll
    for (int it = 0; it < 2; ++it) {    // A: 1024 chunks
      int c = it * 512 + t;
      int row = c >> 3, pslot = c & 7;
      int lslot = pslot ^ (row & 7);
      __builtin_amdgcn_global_load_lds(
          (const __attribute__((address_space(1))) void*)(
              A2 + (size_t)(2 * s + (lslot >> 2)) * 65536 + row * 32 + (lslot & 3) * 8),
          (__attribute__((address_space(3))) void*)(As + buf * 8192 + c * 8), 16, 0, 0);
    }
#pragma unroll
    for (int it = 0; it < 2; ++it) {    // B: 1024 chunks
      int c = it * 512 + t;
      int row = c >> 3, pslot = c & 7;
      int lslot = pslot ^ (row & 7);
      __builtin_amdgcn_global_load_lds(
          (const __attribute__((address_space(1))) void*)(
              B2 + (size_t)(2 * s + (lslot >> 2)) * 16384 + row * 32 + (lslot & 3) * 8),
          (__attribute__((address_space(3))) void*)(Bs + buf * 8192 + c * 8), 16, 0, 0);
    }
  };

  bf16x8 a[4], bb[4];
  auto rd = [&](int buf) {              // 8 ds_read_b128, wave's k-half only
    const u16* Ab = As + buf * 8192;
    const u16* Bb = Bs + buf * 8192;
#pragma unroll
    for (int i = 0; i < 4; ++i) {
      int row = wm * 64 + i * 16 + la;
      int ps = (wk * 4 + q) ^ (row & 7);
      a[i] = *reinterpret_cast<const bf16x8*>(Ab + row * 64 + ps * 8);
    }
#pragma unroll
    for (int j = 0; j < 4; ++j) {
      int row = wn * 64 + j * 16 + la;
      int ps = (wk * 4 + q) ^ (row & 7);
      bb[j] = *reinterpret_cast<const bf16x8*>(Bb + row * 64 + ps * 8);
    }
  };
  auto compute = [&]() {
    if (wn == 0) {                      // rowsum: wk halves partition k
#pragma unroll
      for (int i = 0; i < 4; ++i) {
        float ls = 0.f;
#pragma unroll
        for (int e = 0; e < 8; ++e) ls += (float)a[i][e];
        lacc[i] += ls;
      }
    }
    __builtin_amdgcn_s_setprio(1);
#pragma unroll
    for (int i = 0; i < 4; ++i)
#pragma unroll
      for (int j = 0; j < 4; ++j)
        acc[i][j] = __builtin_amdgcn_mfma_f32_16x16x32_bf16(a[i], bb[j], acc[i][j], 0, 0, 0);
    __builtin_amdgcn_s_setprio(0);
  };

  stage(0); stage(1);                   // 8 loads/thread in flight
  for (int s = 0; s < 30; ++s) {
    VMCNT(4);                           // step s landed; s+1 flying
    __builtin_amdgcn_s_barrier();       // all waves see buf s&1 full
    rd(s & 1);                          // ds_reads of current buf
    LGKMCNT0;                           // my reads landed in regs
    __builtin_amdgcn_s_barrier();       // all waves' reads done -> buf free
    stage(s + 2);                       // overwrite buf s&1
    compute();
  }
  VMCNT(4); __builtin_amdgcn_s_barrier();            // step 30 (buf 0)
  rd(0); LGKMCNT0; __builtin_amdgcn_s_barrier(); compute();
  VMCNT(0); __builtin_amdgcn_s_barrier();            // step 31 (buf 1)
  rd(1); LGKMCNT0; __builtin_amdgcn_s_barrier();     // all reads done pre-overlay
  compute();

  // ---- epilogue: rowsum halves + wk-pair acc reduction via LDS ------
  float l[4];
#pragma unroll
  for (int i = 0; i < 4; ++i) {
    l[i] = lacc[i];
    l[i] += __shfl_xor(l[i], 16);
    l[i] += __shfl_xor(l[i], 32);       // sum across 4 q-lanes (la preserved)
  }
  if (wn == 0 && q == 0) {              // 2 wm x 2 wk waves x 16 la x 4 i
#pragma unroll
    for (int i = 0; i < 4; ++i) larr2[wk][wm * 64 + i * 16 + la] = l[i];
  }
  float* sp = scratch + (wid >> 1) * 4096;   // 16KB per (wm,wn) pair
  if (wk == 1) {
#pragma unroll
    for (int i = 0; i < 4; ++i)
#pragma unroll
      for (int j = 0; j < 4; ++j)
        *reinterpret_cast<f32x4*>(sp + (i * 4 + j) * 256 + lane * 4) = acc[i][j];
  }
  __syncthreads();
  if (wk == 0) {
#pragma unroll
    for (int i = 0; i < 4; ++i)
#pragma unroll
      for (int j = 0; j < 4; ++j) {
        f32x4 o = *reinterpret_cast<const f32x4*>(sp + (i * 4 + j) * 256 + lane * 4);
#pragma unroll
        for (int r = 0; r < 4; ++r) acc[i][j][r] += o[r];
      }
    float* C = out + ((size_t)b * 2048 + bm) * 512;
    const int r0 = q * 4, cn = lane & 15;
    float inv[4][4];
#pragma unroll
    for (int i = 0; i < 4; ++i)
#pragma unroll
      for (int r = 0; r < 4; ++r) {
        int row = wm * 64 + i * 16 + r0 + r;
        inv[i][r] = 1.0f / (larr2[0][row] + larr2[1][row]);
      }
#pragma unroll
    for (int i = 0; i < 4; ++i)
#pragma unroll
      for (int j = 0; j < 4; ++j)
#pragma unroll
        for (int r = 0; r < 4; ++r) {
          int m = wm * 64 + 16 * i + r0 + r;
          int n = bn + 64 * wn + 16 * j + cn;
          C[(size_t)m * 512 + n] = acc[i][j][r] * inv[i][r];
        }
  }
}

extern "C" void kernel_launch(void* const* d_in, const int* in_sizes, int n_in,
                              void* d_out, int out_size, void* d_ws, size_t ws_size,
                              hipStream_t stream) {
  const float* x  = (const float*)d_in[0];
  const float* Wq = (const float*)d_in[1];
  const float* Wk = (const float*)d_in[2];
  const float* Wv = (const float*)d_in[3];
  float* out = (float*)d_out;

  // ws layout: Xb bf16[16384][512] | Wt bf16[3][512][512] | Q | K | Vt2 | S2
  char* p = (char*)d_ws;
  u16* Xb = (u16*)p;            p += (size_t)16384 * 512 * 2;
  u16* Wt = (u16*)p;            p += (size_t)3 * 512 * 512 * 2;
  u16* Q  = (u16*)p;            p += (size_t)16384 * 512 * 2;
  u16* K  = (u16*)p;            p += (size_t)16384 * 512 * 2;
  u16* Vt2 = (u16*)p;           p += (size_t)16384 * 512 * 2;
  u16* S2 = (u16*)p;

  cast_x_kernel<<<dim3(8192), dim3(256), 0, stream>>>(x, Xb, 16384 * 512 / 4);
  transpose_w_kernel<<<dim3(16, 16, 3), dim3(32, 32), 0, stream>>>(Wq, Wk, Wv, Wt);
  qkv_kernel<<<dim3(4, 128, 3), dim3(256), 0, stream>>>(Xb, Wt, Q, K, Vt2);
  scores_kernel<<<dim3(8, 8, 8), dim3(1024), 0, stream>>>(Q, K, S2);
  pv_kernel<<<dim3(512), dim3(512), 0, stream>>>(S2, Vt2, out);
}